// Round 1
// baseline (1485.110 us; speedup 1.0000x reference)
//
#include <hip/hip_runtime.h>

#define N_NODES 50000
#define N_EDGES 800000
#define D 128

// ---------------------------------------------------------------------------
// deg[v] = number of edges with dst == v  (stored as float, reused all layers)
// ---------------------------------------------------------------------------
__global__ void deg_kernel(const int* __restrict__ dst, float* __restrict__ deg) {
    int e = blockIdx.x * blockDim.x + threadIdx.x;
    if (e < N_EDGES) atomicAdd(&deg[dst[e]], 1.0f);
}

// ---------------------------------------------------------------------------
// agg[dst[e]][d] += h[src[e]][d]  — one thread per (edge, dim)
// ---------------------------------------------------------------------------
__global__ void scatter_kernel(const float* __restrict__ h,
                               const int* __restrict__ src,
                               const int* __restrict__ dst,
                               float* __restrict__ agg) {
    long long idx = (long long)blockIdx.x * blockDim.x + threadIdx.x;
    int e = (int)(idx >> 7);
    int d = (int)(idx & 127);
    if (e < N_EDGES) {
        int s = src[e];
        int t = dst[e];
        atomicAdd(&agg[t * D + d], h[s * D + d]);
    }
}

// ---------------------------------------------------------------------------
// Wt[k][o] = W[o][k]  (tiny, 128x128)
// ---------------------------------------------------------------------------
__global__ void transpose_kernel(const float* __restrict__ W, float* __restrict__ Wt) {
    int k = blockIdx.x;      // 0..127
    int o = threadIdx.x;     // 0..127
    Wt[k * D + o] = W[o * D + k];
}

// ---------------------------------------------------------------------------
// out[v][o] = sum_k (agg[v][k] - deg[v]*h[v][k]) * Wt[k][o] + deg[v]*b[o]
// one block (128 threads) per node; t-row staged in LDS, Wt read coalesced
// ---------------------------------------------------------------------------
__global__ void linear_kernel(const float* __restrict__ agg,
                              const float* __restrict__ h,
                              const float* __restrict__ deg,
                              const float* __restrict__ Wt,
                              const float* __restrict__ b,
                              float* __restrict__ out) {
    __shared__ float t[D];
    int v = blockIdx.x;
    int o = threadIdx.x;
    float dv = deg[v];
    int base = v * D;
    t[o] = agg[base + o] - dv * h[base + o];
    __syncthreads();
    float acc = dv * b[o];
#pragma unroll 8
    for (int k = 0; k < D; ++k) {
        acc += t[k] * Wt[k * D + o];
    }
    out[base + o] = acc;
}

extern "C" void kernel_launch(void* const* d_in, const int* in_sizes, int n_in,
                              void* d_out, int out_size, void* d_ws, size_t ws_size,
                              hipStream_t stream) {
    const float* x  = (const float*)d_in[0];
    const float* W1 = (const float*)d_in[1];
    const float* b1 = (const float*)d_in[2];
    const float* W2 = (const float*)d_in[3];
    const float* b2 = (const float*)d_in[4];
    const float* W3 = (const float*)d_in[5];
    const float* b3 = (const float*)d_in[6];
    const int*   ei = (const int*)d_in[7];      // [2, E] int32
    // d_in[8] = edge_index_inter — unused by the reference

    const int* src = ei;            // row 0
    const int* dst = ei + N_EDGES;  // row 1

    float* out = (float*)d_out;

    // workspace layout (bytes):
    //   [0, 200704)                     deg   (50000 floats, padded to 256B)
    //   [200704, +25.6MB)               agg   (N*D floats)
    //   next 25.6MB                     h1
    //   next 25.6MB                     h2
    //   next 64KB                       Wt
    char* ws = (char*)d_ws;
    float* deg = (float*)ws;
    float* agg = (float*)(ws + 200704);
    float* h1  = agg + (size_t)N_NODES * D;
    float* h2  = h1 + (size_t)N_NODES * D;
    float* Wt  = h2 + (size_t)N_NODES * D;

    const size_t feat_bytes = (size_t)N_NODES * D * sizeof(float);

    // degree (once, shared across layers)
    hipMemsetAsync(deg, 0, N_NODES * sizeof(float), stream);
    deg_kernel<<<(N_EDGES + 255) / 256, 256, 0, stream>>>(dst, deg);

    const int scatter_blocks = (int)(((long long)N_EDGES * D + 255) / 256);

    // ---- layer 1: x -> h1 ----
    hipMemsetAsync(agg, 0, feat_bytes, stream);
    scatter_kernel<<<scatter_blocks, 256, 0, stream>>>(x, src, dst, agg);
    transpose_kernel<<<D, D, 0, stream>>>(W1, Wt);
    linear_kernel<<<N_NODES, D, 0, stream>>>(agg, x, deg, Wt, b1, h1);

    // ---- layer 2: h1 -> h2 ----
    hipMemsetAsync(agg, 0, feat_bytes, stream);
    scatter_kernel<<<scatter_blocks, 256, 0, stream>>>(h1, src, dst, agg);
    transpose_kernel<<<D, D, 0, stream>>>(W2, Wt);
    linear_kernel<<<N_NODES, D, 0, stream>>>(agg, h1, deg, Wt, b2, h2);

    // ---- layer 3: h2 -> out ----
    hipMemsetAsync(agg, 0, feat_bytes, stream);
    scatter_kernel<<<scatter_blocks, 256, 0, stream>>>(h2, src, dst, agg);
    transpose_kernel<<<D, D, 0, stream>>>(W3, Wt);
    linear_kernel<<<N_NODES, D, 0, stream>>>(agg, h2, deg, Wt, b3, out);
}

// Round 2
// 567.838 us; speedup vs baseline: 2.6154x; 2.6154x over previous
//
#include <hip/hip_runtime.h>

#define N_NODES 50000
#define N_EDGES 800000
#define D 128
#define TN 16   // nodes per block in the fused layer kernel

// ---------------------------------------------------------------------------
// CSR build step 1: counts[v] = #edges with dst == v
// ---------------------------------------------------------------------------
__global__ void count_kernel(const int* __restrict__ dst, int* __restrict__ counts) {
    int e = blockIdx.x * blockDim.x + threadIdx.x;
    if (e < N_EDGES) atomicAdd(&counts[dst[e]], 1);
}

// ---------------------------------------------------------------------------
// CSR build step 2: exclusive scan of counts -> offsets[N+1], cursor copy.
// Single block of 1024 threads; each thread owns a contiguous chunk.
// ---------------------------------------------------------------------------
__global__ void scan_kernel(const int* __restrict__ counts,
                            int* __restrict__ offsets,
                            int* __restrict__ cursor) {
    __shared__ int sums[1024];
    const int tid = threadIdx.x;
    const int CH = (N_NODES + 1023) / 1024;   // 49
    const int start = tid * CH;
    const int end = min(start + CH, N_NODES);

    int s = 0;
    for (int i = start; i < end; ++i) s += counts[i];
    sums[tid] = s;
    __syncthreads();

    // Hillis-Steele inclusive scan
    for (int off = 1; off < 1024; off <<= 1) {
        int v = 0;
        if (tid >= off) v = sums[tid - off];
        __syncthreads();
        if (tid >= off) sums[tid] += v;
        __syncthreads();
    }

    int run = sums[tid] - s;   // exclusive prefix for this chunk
    for (int i = start; i < end; ++i) {
        offsets[i] = run;
        cursor[i] = run;
        run += counts[i];
    }
    if (tid == 0) offsets[N_NODES] = sums[1023];
}

// ---------------------------------------------------------------------------
// CSR build step 3: bucket the source node of every edge by its dst
// ---------------------------------------------------------------------------
__global__ void fill_kernel(const int* __restrict__ src, const int* __restrict__ dst,
                            int* __restrict__ cursor, int* __restrict__ esrc) {
    int e = blockIdx.x * blockDim.x + threadIdx.x;
    if (e < N_EDGES) {
        int v = dst[e];
        int p = atomicAdd(&cursor[v], 1);
        esrc[p] = src[e];
    }
}

// ---------------------------------------------------------------------------
// Wt[k][o] = W[o][k]  (tiny, 128x128)
// ---------------------------------------------------------------------------
__global__ void transpose_kernel(const float* __restrict__ W, float* __restrict__ Wt) {
    int k = blockIdx.x;
    int o = threadIdx.x;
    Wt[k * D + o] = W[o * D + k];
}

// ---------------------------------------------------------------------------
// Fused layer: out[v] = (sum_{e in CSR[v]} h[src_e] - deg[v]*h[v]) @ Wt + deg[v]*b
//
// Block = 256 threads (4 waves), TN=16 nodes per block.
// Phase 1 (gather): wave w handles nodes w*4..w*4+3; 64 lanes read a full
//   128-float row as float2 each (512 B/wave/edge, coalesced). Unroll-2 for
//   two rows in flight. t row staged in LDS (padded stride 130).
// Phase 2 (matvec): thread (half, o) computes 8 (node, o) outputs; t reads
//   are wave-broadcast (same address per half) -> conflict-free; Wt reads
//   coalesced from L2.
// ---------------------------------------------------------------------------
__global__ __launch_bounds__(256) void gnn_layer_kernel(
    const float* __restrict__ h,
    const int* __restrict__ offsets,
    const int* __restrict__ esrc,
    const float* __restrict__ Wt,
    const float* __restrict__ b,
    float* __restrict__ out) {

    __shared__ float t[TN][D + 2];   // stride 130: conflict-free, float2-aligned
    __shared__ float degf[TN];

    const int tid = threadIdx.x;
    const int wave = tid >> 6;
    const int lane = tid & 63;
    const int vbase = blockIdx.x * TN;

    // ---- phase 1: gather ----
    for (int j = wave * 4; j < wave * 4 + 4; ++j) {
        const int v = vbase + j;
        const int beg = offsets[v];
        const int end = offsets[v + 1];

        float2 acc0 = {0.f, 0.f}, acc1 = {0.f, 0.f};
        int e = beg;
        for (; e + 2 <= end; e += 2) {
            int s0 = esrc[e];
            int s1 = esrc[e + 1];
            float2 a = *(const float2*)(h + (size_t)s0 * D + 2 * lane);
            float2 c = *(const float2*)(h + (size_t)s1 * D + 2 * lane);
            acc0.x += a.x; acc0.y += a.y;
            acc1.x += c.x; acc1.y += c.y;
        }
        if (e < end) {
            int s0 = esrc[e];
            float2 a = *(const float2*)(h + (size_t)s0 * D + 2 * lane);
            acc0.x += a.x; acc0.y += a.y;
        }
        const float dv = (float)(end - beg);
        float2 hv = *(const float2*)(h + (size_t)v * D + 2 * lane);
        float2 tv;
        tv.x = acc0.x + acc1.x - dv * hv.x;
        tv.y = acc0.y + acc1.y - dv * hv.y;
        *(float2*)&t[j][2 * lane] = tv;
        if (lane == 0) degf[j] = dv;
    }
    __syncthreads();

    // ---- phase 2: matvec  out[v][o] = sum_k t[v][k]*Wt[k][o] + deg*b[o] ----
    const int o = tid & 127;
    const int half = tid >> 7;        // 0 or 1 -> nodes half*8 .. half*8+7
    const float bo = b[o];

    float acc[8];
#pragma unroll
    for (int j = 0; j < 8; ++j) acc[j] = degf[half * 8 + j] * bo;

    for (int k = 0; k < D; ++k) {
        const float w = Wt[k * D + o];
#pragma unroll
        for (int j = 0; j < 8; ++j) acc[j] += t[half * 8 + j][k] * w;
    }

#pragma unroll
    for (int j = 0; j < 8; ++j) {
        const int v = vbase + half * 8 + j;
        out[(size_t)v * D + o] = acc[j];
    }
}

extern "C" void kernel_launch(void* const* d_in, const int* in_sizes, int n_in,
                              void* d_out, int out_size, void* d_ws, size_t ws_size,
                              hipStream_t stream) {
    const float* x  = (const float*)d_in[0];
    const float* W1 = (const float*)d_in[1];
    const float* b1 = (const float*)d_in[2];
    const float* W2 = (const float*)d_in[3];
    const float* b2 = (const float*)d_in[4];
    const float* W3 = (const float*)d_in[5];
    const float* b3 = (const float*)d_in[6];
    const int*   ei = (const int*)d_in[7];      // [2, E] int32
    // d_in[8] = edge_index_inter — unused by the reference

    const int* src = ei;            // row 0
    const int* dst = ei + N_EDGES;  // row 1
    float* out = (float*)d_out;

    // workspace layout (256B-aligned slabs)
    char* ws = (char*)d_ws;
    int* counts  = (int*)ws;                          ws += 204800;   // N ints
    int* offsets = (int*)ws;                          ws += 204800;   // N+1 ints
    int* cursor  = (int*)ws;                          ws += 204800;   // N ints
    int* esrc    = (int*)ws;                          ws += (size_t)N_EDGES * 4;  // 3.2MB
    float* Wt    = (float*)ws;                        ws += D * D * 4;            // 64KB
    float* h1    = (float*)ws;                        ws += (size_t)N_NODES * D * 4;
    float* h2    = (float*)ws;

    // ---- CSR build (once; reused by all 3 layers) ----
    hipMemsetAsync(counts, 0, N_NODES * sizeof(int), stream);
    count_kernel<<<(N_EDGES + 255) / 256, 256, 0, stream>>>(dst, counts);
    scan_kernel<<<1, 1024, 0, stream>>>(counts, offsets, cursor);
    fill_kernel<<<(N_EDGES + 255) / 256, 256, 0, stream>>>(src, dst, cursor, esrc);

    const int blocks = N_NODES / TN;   // 3125

    // ---- layer 1: x -> h1 ----
    transpose_kernel<<<D, D, 0, stream>>>(W1, Wt);
    gnn_layer_kernel<<<blocks, 256, 0, stream>>>(x, offsets, esrc, Wt, b1, h1);

    // ---- layer 2: h1 -> h2 ----
    transpose_kernel<<<D, D, 0, stream>>>(W2, Wt);
    gnn_layer_kernel<<<blocks, 256, 0, stream>>>(h1, offsets, esrc, Wt, b2, h2);

    // ---- layer 3: h2 -> out ----
    transpose_kernel<<<D, D, 0, stream>>>(W3, Wt);
    gnn_layer_kernel<<<blocks, 256, 0, stream>>>(h2, offsets, esrc, Wt, b3, out);
}

// Round 3
// 446.710 us; speedup vs baseline: 3.3246x; 1.2712x over previous
//
#include <hip/hip_runtime.h>

#define N_NODES 50000
#define N_EDGES 800000
#define D 128
#define TN 16                 // nodes per block in the fused layer kernel
#define SCAN_BLOCKS 196       // ceil(50000/256)

// ---------------------------------------------------------------------------
// CSR build step 1: counts[v] = #edges with dst == v
// ---------------------------------------------------------------------------
__global__ void count_kernel(const int* __restrict__ dst, int* __restrict__ counts) {
    int e = blockIdx.x * blockDim.x + threadIdx.x;
    if (e < N_EDGES) atomicAdd(&counts[dst[e]], 1);
}

// ---------------------------------------------------------------------------
// Scan A: per-block (256-wide) sums of counts -> bsum[196]
// ---------------------------------------------------------------------------
__global__ void block_sum_kernel(const int* __restrict__ counts, int* __restrict__ bsum) {
    __shared__ int red[256];
    const int tid = threadIdx.x;
    const int i = blockIdx.x * 256 + tid;
    red[tid] = (i < N_NODES) ? counts[i] : 0;
    __syncthreads();
    for (int s = 128; s > 0; s >>= 1) {
        if (tid < s) red[tid] += red[tid + s];
        __syncthreads();
    }
    if (tid == 0) bsum[blockIdx.x] = red[0];
}

// ---------------------------------------------------------------------------
// Scan B: exclusive scan of the 196 block sums (single tiny block);
// also writes offsets[N_NODES] = total edge count.
// ---------------------------------------------------------------------------
__global__ void bsum_scan_kernel(const int* __restrict__ bsum,
                                 int* __restrict__ bpre,
                                 int* __restrict__ offsets) {
    __shared__ int s[256];
    const int tid = threadIdx.x;
    const int v = (tid < SCAN_BLOCKS) ? bsum[tid] : 0;
    s[tid] = v;
    __syncthreads();
    for (int off = 1; off < 256; off <<= 1) {
        int a = (tid >= off) ? s[tid - off] : 0;
        __syncthreads();
        s[tid] += a;
        __syncthreads();
    }
    bpre[tid] = s[tid] - v;      // exclusive prefix
    if (tid == 255) offsets[N_NODES] = s[255];
}

// ---------------------------------------------------------------------------
// Scan C: per-block exclusive scan + block prefix -> offsets, cursor
// ---------------------------------------------------------------------------
__global__ void scatter_offsets_kernel(const int* __restrict__ counts,
                                       const int* __restrict__ bpre,
                                       int* __restrict__ offsets,
                                       int* __restrict__ cursor) {
    __shared__ int s[256];
    const int tid = threadIdx.x;
    const int i = blockIdx.x * 256 + tid;
    const int v = (i < N_NODES) ? counts[i] : 0;
    s[tid] = v;
    __syncthreads();
    for (int off = 1; off < 256; off <<= 1) {
        int a = (tid >= off) ? s[tid - off] : 0;
        __syncthreads();
        s[tid] += a;
        __syncthreads();
    }
    const int excl = s[tid] - v + bpre[blockIdx.x];
    if (i < N_NODES) {
        offsets[i] = excl;
        cursor[i] = excl;
    }
}

// ---------------------------------------------------------------------------
// CSR build step 3: bucket the source node of every edge by its dst
// ---------------------------------------------------------------------------
__global__ void fill_kernel(const int* __restrict__ src, const int* __restrict__ dst,
                            int* __restrict__ cursor, int* __restrict__ esrc) {
    int e = blockIdx.x * blockDim.x + threadIdx.x;
    if (e < N_EDGES) {
        int v = dst[e];
        int p = atomicAdd(&cursor[v], 1);
        esrc[p] = src[e];
    }
}

// ---------------------------------------------------------------------------
// Wt[k][o] = W[o][k]  (tiny, 128x128) — all three weights in one dispatch
// ---------------------------------------------------------------------------
__global__ void transpose3_kernel(const float* __restrict__ W1,
                                  const float* __restrict__ W2,
                                  const float* __restrict__ W3,
                                  float* __restrict__ Wt /* 3 x D x D */) {
    int k = blockIdx.x;          // 0..127
    int w = blockIdx.y;          // 0..2
    int o = threadIdx.x;         // 0..127
    const float* W = (w == 0) ? W1 : (w == 1) ? W2 : W3;
    Wt[(size_t)w * D * D + k * D + o] = W[o * D + k];
}

// ---------------------------------------------------------------------------
// Fused layer: out[v] = (sum_{e in CSR[v]} h[src_e] - deg[v]*h[v]) @ Wt + deg[v]*b
//
// Block = 256 threads (4 waves), TN=16 nodes/block.
// Phase 1 (gather): wave w handles nodes w*4..w*4+3. Edge-paired float4
//   loads: lanes 0-31 cover edge e's row (q*4..q*4+3), lanes 32-63 edge e+1's.
//   One wave-load = 2 rows (1 KB). Unroll x2 -> 4 rows in flight/wave.
//   Halves combined via shfl_xor(32); lanes 0-31 write t row (stride 132,
//   16B-aligned for b128 LDS writes).
// Phase 2 (matvec): thread (half,o) computes 8 (node,o) outputs; t reads are
//   wave-broadcast (conflict-free), Wt reads coalesced (L2-resident).
// ---------------------------------------------------------------------------
__global__ __launch_bounds__(256) void gnn_layer_kernel(
    const float* __restrict__ h,
    const int* __restrict__ offsets,
    const int* __restrict__ esrc,
    const float* __restrict__ Wt,
    const float* __restrict__ b,
    float* __restrict__ out) {

    __shared__ __align__(16) float t[TN][D + 4];   // stride 132 floats = 528B
    __shared__ float degf[TN];

    const int tid = threadIdx.x;
    const int wave = tid >> 6;
    const int lane = tid & 63;
    const int sub = lane >> 5;        // 0: even edge, 1: odd edge
    const int q = lane & 31;          // float4 slot within the row
    const int vbase = blockIdx.x * TN;

    // ---- phase 1: gather ----
    for (int j = wave * 4; j < wave * 4 + 4; ++j) {
        const int v = vbase + j;
        const int beg = offsets[v];
        const int end = offsets[v + 1];

        float ax = 0.f, ay = 0.f, az = 0.f, aw = 0.f;
        float bx = 0.f, by = 0.f, bz = 0.f, bw = 0.f;

        for (int e = beg; e < end; e += 4) {
            const int e0 = e + sub;
            const int e1 = e + 2 + sub;
            if (e0 < end) {
                const int s0 = esrc[e0];
                const float4 r = *(const float4*)(h + (size_t)s0 * D + 4 * q);
                ax += r.x; ay += r.y; az += r.z; aw += r.w;
            }
            if (e1 < end) {
                const int s1 = esrc[e1];
                const float4 r = *(const float4*)(h + (size_t)s1 * D + 4 * q);
                bx += r.x; by += r.y; bz += r.z; bw += r.w;
            }
        }
        ax += bx; ay += by; az += bz; aw += bw;

        // combine the two half-wave partial sums (lane L <-> L^32)
        ax += __shfl_xor(ax, 32, 64);
        ay += __shfl_xor(ay, 32, 64);
        az += __shfl_xor(az, 32, 64);
        aw += __shfl_xor(aw, 32, 64);

        const float dv = (float)(end - beg);
        if (sub == 0) {
            const float4 hv = *(const float4*)(h + (size_t)v * D + 4 * q);
            float4 tv;
            tv.x = ax - dv * hv.x;
            tv.y = ay - dv * hv.y;
            tv.z = az - dv * hv.z;
            tv.w = aw - dv * hv.w;
            *(float4*)&t[j][4 * q] = tv;
        }
        if (lane == 0) degf[j] = dv;
    }
    __syncthreads();

    // ---- phase 2: matvec  out[v][o] = sum_k t[v][k]*Wt[k][o] + deg*b[o] ----
    const int o = tid & 127;
    const int half = tid >> 7;        // nodes half*8 .. half*8+7
    const float bo = b[o];

    float acc[8];
#pragma unroll
    for (int j = 0; j < 8; ++j) acc[j] = degf[half * 8 + j] * bo;

    for (int k = 0; k < D; ++k) {
        const float w = Wt[k * D + o];
#pragma unroll
        for (int j = 0; j < 8; ++j) acc[j] += t[half * 8 + j][k] * w;
    }

#pragma unroll
    for (int j = 0; j < 8; ++j) {
        const int v = vbase + half * 8 + j;
        out[(size_t)v * D + o] = acc[j];
    }
}

extern "C" void kernel_launch(void* const* d_in, const int* in_sizes, int n_in,
                              void* d_out, int out_size, void* d_ws, size_t ws_size,
                              hipStream_t stream) {
    const float* x  = (const float*)d_in[0];
    const float* W1 = (const float*)d_in[1];
    const float* b1 = (const float*)d_in[2];
    const float* W2 = (const float*)d_in[3];
    const float* b2 = (const float*)d_in[4];
    const float* W3 = (const float*)d_in[5];
    const float* b3 = (const float*)d_in[6];
    const int*   ei = (const int*)d_in[7];      // [2, E] int32
    // d_in[8] = edge_index_inter — unused by the reference

    const int* src = ei;            // row 0
    const int* dst = ei + N_EDGES;  // row 1
    float* out = (float*)d_out;

    // workspace layout (256B-aligned slabs)
    char* ws = (char*)d_ws;
    int* counts  = (int*)ws;                      ws += 204800;               // N ints
    int* offsets = (int*)ws;                      ws += 204800;               // N+1 ints
    int* cursor  = (int*)ws;                      ws += 204800;               // N ints
    int* bsum    = (int*)ws;                      ws += 1024;                 // 196 ints
    int* bpre    = (int*)ws;                      ws += 1024;                 // 256 ints
    int* esrc    = (int*)ws;                      ws += (size_t)N_EDGES * 4;  // 3.2MB
    float* Wt    = (float*)ws;                    ws += 3 * D * D * 4;        // 192KB
    float* h1    = (float*)ws;                    ws += (size_t)N_NODES * D * 4;
    float* h2    = (float*)ws;

    // ---- CSR build (once; reused by all 3 layers) ----
    hipMemsetAsync(counts, 0, N_NODES * sizeof(int), stream);
    count_kernel<<<(N_EDGES + 255) / 256, 256, 0, stream>>>(dst, counts);
    block_sum_kernel<<<SCAN_BLOCKS, 256, 0, stream>>>(counts, bsum);
    bsum_scan_kernel<<<1, 256, 0, stream>>>(bsum, bpre, offsets);
    scatter_offsets_kernel<<<SCAN_BLOCKS, 256, 0, stream>>>(counts, bpre, offsets, cursor);
    fill_kernel<<<(N_EDGES + 255) / 256, 256, 0, stream>>>(src, dst, cursor, esrc);

    // all three weight transposes in one dispatch
    transpose3_kernel<<<dim3(D, 3), D, 0, stream>>>(W1, W2, W3, Wt);

    const int blocks = N_NODES / TN;   // 3125

    gnn_layer_kernel<<<blocks, 256, 0, stream>>>(x,  offsets, esrc, Wt,            b1, h1);
    gnn_layer_kernel<<<blocks, 256, 0, stream>>>(h1, offsets, esrc, Wt + D * D,     b2, h2);
    gnn_layer_kernel<<<blocks, 256, 0, stream>>>(h2, offsets, esrc, Wt + 2 * D * D, b3, out);
}

// Round 4
// 373.813 us; speedup vs baseline: 3.9729x; 1.1950x over previous
//
#include <hip/hip_runtime.h>

#define N_NODES 50000
#define N_EDGES 800000
#define D 128
#define TN 16                 // nodes per block in the fused layer kernel
#define TSTR 136              // LDS row stride in bf16 elems (272B: 16B-aligned, low-conflict)
#define SCAN_BLOCKS 196       // ceil(50000/256)

typedef __attribute__((ext_vector_type(8))) short bf16x8;
typedef __attribute__((ext_vector_type(4))) float f32x4;

__device__ __forceinline__ unsigned short f32_to_bf16_rne(float f) {
    unsigned u = __float_as_uint(f);
    u += 0x7fffu + ((u >> 16) & 1u);
    return (unsigned short)(u >> 16);
}

// ---------------------------------------------------------------------------
// CSR build step 1: counts[v] = #edges with dst == v
// ---------------------------------------------------------------------------
__global__ void count_kernel(const int* __restrict__ dst, int* __restrict__ counts) {
    int e = blockIdx.x * blockDim.x + threadIdx.x;
    if (e < N_EDGES) atomicAdd(&counts[dst[e]], 1);
}

// ---------------------------------------------------------------------------
// Scan A: per-block (256-wide) sums of counts -> bsum[196]
// ---------------------------------------------------------------------------
__global__ void block_sum_kernel(const int* __restrict__ counts, int* __restrict__ bsum) {
    __shared__ int red[256];
    const int tid = threadIdx.x;
    const int i = blockIdx.x * 256 + tid;
    red[tid] = (i < N_NODES) ? counts[i] : 0;
    __syncthreads();
    for (int s = 128; s > 0; s >>= 1) {
        if (tid < s) red[tid] += red[tid + s];
        __syncthreads();
    }
    if (tid == 0) bsum[blockIdx.x] = red[0];
}

// ---------------------------------------------------------------------------
// Scan B: exclusive scan of the 196 block sums (single tiny block)
// ---------------------------------------------------------------------------
__global__ void bsum_scan_kernel(const int* __restrict__ bsum,
                                 int* __restrict__ bpre,
                                 int* __restrict__ offsets) {
    __shared__ int s[256];
    const int tid = threadIdx.x;
    const int v = (tid < SCAN_BLOCKS) ? bsum[tid] : 0;
    s[tid] = v;
    __syncthreads();
    for (int off = 1; off < 256; off <<= 1) {
        int a = (tid >= off) ? s[tid - off] : 0;
        __syncthreads();
        s[tid] += a;
        __syncthreads();
    }
    bpre[tid] = s[tid] - v;
    if (tid == 255) offsets[N_NODES] = s[255];
}

// ---------------------------------------------------------------------------
// Scan C: per-block exclusive scan + block prefix -> offsets, cursor
// ---------------------------------------------------------------------------
__global__ void scatter_offsets_kernel(const int* __restrict__ counts,
                                       const int* __restrict__ bpre,
                                       int* __restrict__ offsets,
                                       int* __restrict__ cursor) {
    __shared__ int s[256];
    const int tid = threadIdx.x;
    const int i = blockIdx.x * 256 + tid;
    const int v = (i < N_NODES) ? counts[i] : 0;
    s[tid] = v;
    __syncthreads();
    for (int off = 1; off < 256; off <<= 1) {
        int a = (tid >= off) ? s[tid - off] : 0;
        __syncthreads();
        s[tid] += a;
        __syncthreads();
    }
    const int excl = s[tid] - v + bpre[blockIdx.x];
    if (i < N_NODES) {
        offsets[i] = excl;
        cursor[i] = excl;
    }
}

// ---------------------------------------------------------------------------
// CSR build step 3: bucket the source node of every edge by its dst
// ---------------------------------------------------------------------------
__global__ void fill_kernel(const int* __restrict__ src, const int* __restrict__ dst,
                            int* __restrict__ cursor, int* __restrict__ esrc) {
    int e = blockIdx.x * blockDim.x + threadIdx.x;
    if (e < N_EDGES) {
        int v = dst[e];
        int p = atomicAdd(&cursor[v], 1);
        esrc[p] = src[e];
    }
}

// ---------------------------------------------------------------------------
// Pre-pack all 3 weights as bf16 MFMA B-fragments in exact lane order.
// B[k][n] for tile nt, chunk kc lives at Wb[((w*8+nt)*4+kc)*512 + lane*8 + j]
// with n = lane&15, k = kc*32 + (lane>>4)*8 + j, and B[k][n] = W[nt*16+n][k].
// ---------------------------------------------------------------------------
__global__ void wfrag_kernel(const float* __restrict__ W1,
                             const float* __restrict__ W2,
                             const float* __restrict__ W3,
                             unsigned short* __restrict__ Wb) {
    const int w = blockIdx.x >> 7;      // 0..2
    const int o = blockIdx.x & 127;     // 0..127
    const int k = threadIdx.x;          // 0..127
    const float* W = (w == 0) ? W1 : (w == 1) ? W2 : W3;
    const unsigned short v = f32_to_bf16_rne(W[o * D + k]);
    const int nt = o >> 4, n = o & 15;
    const int kc = k >> 5, kr = k & 31, quad = kr >> 3, j = kr & 7;
    const int lane = quad * 16 + n;
    Wb[(((size_t)w * 8 + nt) * 4 + kc) * 512 + lane * 8 + j] = v;
}

// ---------------------------------------------------------------------------
// x (fp32) -> xb (bf16), 4 elems/thread
// ---------------------------------------------------------------------------
__global__ void cvt_bf16_kernel(const float* __restrict__ in, unsigned short* __restrict__ out) {
    const int i = blockIdx.x * blockDim.x + threadIdx.x;
    const float4 v = *(const float4*)(in + (size_t)i * 4);
    unsigned p0 = (unsigned)f32_to_bf16_rne(v.x) | ((unsigned)f32_to_bf16_rne(v.y) << 16);
    unsigned p1 = (unsigned)f32_to_bf16_rne(v.z) | ((unsigned)f32_to_bf16_rne(v.w) << 16);
    *(uint2*)(out + (size_t)i * 4) = make_uint2(p0, p1);
}

// ---------------------------------------------------------------------------
// Fused layer: out[v] = (sum h[src_e] - deg[v]*h[v]) @ W^T + deg[v]*b
// Phase 1: bf16 gather (256B/row, 32 lanes x 8B), fp32 accumulate,
//          edge-paired across half-waves, shfl_xor(32) combine,
//          t stored to LDS as bf16 (one rounding).
// Phase 2: 16x128x128 GEMM via 8 v_mfma_f32_16x16x32_bf16 per wave
//          (wave w handles N-tiles 2w, 2w+1), fp32 epilogue with deg*b.
// ---------------------------------------------------------------------------
template <bool OUT_BF16>
__global__ __launch_bounds__(256) void gnn_layer_kernel(
    const unsigned short* __restrict__ hb,     // [N][D] bf16
    const int* __restrict__ offsets,
    const int* __restrict__ esrc,
    const unsigned short* __restrict__ Wb,     // fragment-ordered bf16 (this layer)
    const float* __restrict__ bias,
    float* __restrict__ outf,
    unsigned short* __restrict__ outb) {

    __shared__ __align__(16) unsigned short tb[TN][TSTR];
    __shared__ float degf[TN];

    const int tid = threadIdx.x;
    const int wave = tid >> 6;
    const int lane = tid & 63;
    const int sub = lane >> 5;        // edge parity within pair
    const int q = lane & 31;          // dim group: dims 4q..4q+3
    const int vbase = blockIdx.x * TN;

    // ---- phase 1: gather ----
    for (int j = wave * 4; j < wave * 4 + 4; ++j) {
        const int v = vbase + j;
        const int beg = offsets[v];
        const int end = offsets[v + 1];

        float ax = 0.f, ay = 0.f, az = 0.f, aw = 0.f;
        float bx = 0.f, by = 0.f, bz = 0.f, bw = 0.f;

        for (int e = beg; e < end; e += 4) {
            const int e0 = e + sub;
            const int e1 = e + 2 + sub;
            if (e0 < end) {
                const uint2 r = *(const uint2*)(hb + (size_t)esrc[e0] * D + 4 * q);
                ax += __uint_as_float(r.x << 16);
                ay += __uint_as_float(r.x & 0xffff0000u);
                az += __uint_as_float(r.y << 16);
                aw += __uint_as_float(r.y & 0xffff0000u);
            }
            if (e1 < end) {
                const uint2 r = *(const uint2*)(hb + (size_t)esrc[e1] * D + 4 * q);
                bx += __uint_as_float(r.x << 16);
                by += __uint_as_float(r.x & 0xffff0000u);
                bz += __uint_as_float(r.y << 16);
                bw += __uint_as_float(r.y & 0xffff0000u);
            }
        }
        ax += bx; ay += by; az += bz; aw += bw;

        ax += __shfl_xor(ax, 32, 64);
        ay += __shfl_xor(ay, 32, 64);
        az += __shfl_xor(az, 32, 64);
        aw += __shfl_xor(aw, 32, 64);

        const float dv = (float)(end - beg);
        if (sub == 0) {
            const uint2 r = *(const uint2*)(hb + (size_t)v * D + 4 * q);
            const float tx = ax - dv * __uint_as_float(r.x << 16);
            const float ty = ay - dv * __uint_as_float(r.x & 0xffff0000u);
            const float tz = az - dv * __uint_as_float(r.y << 16);
            const float tw = aw - dv * __uint_as_float(r.y & 0xffff0000u);
            unsigned p0 = (unsigned)f32_to_bf16_rne(tx) | ((unsigned)f32_to_bf16_rne(ty) << 16);
            unsigned p1 = (unsigned)f32_to_bf16_rne(tz) | ((unsigned)f32_to_bf16_rne(tw) << 16);
            *(uint2*)&tb[j][4 * q] = make_uint2(p0, p1);
        }
        if (lane == 0) degf[j] = dv;
    }
    __syncthreads();

    // ---- phase 2: MFMA GEMM  out[16][128] = t[16][128] @ Wt[128][128] ----
    const int n16 = lane & 15;
    const int quad = lane >> 4;

    bf16x8 afrag[4];
#pragma unroll
    for (int kc = 0; kc < 4; ++kc)
        afrag[kc] = *(const bf16x8*)&tb[n16][kc * 32 + quad * 8];

#pragma unroll
    for (int i = 0; i < 2; ++i) {
        const int nt = wave * 2 + i;
        f32x4 acc = {0.f, 0.f, 0.f, 0.f};
#pragma unroll
        for (int kc = 0; kc < 4; ++kc) {
            const bf16x8 bfrag = *(const bf16x8*)&Wb[((nt * 4 + kc) * 64 + lane) * 8];
            acc = __builtin_amdgcn_mfma_f32_16x16x32_bf16(afrag[kc], bfrag, acc, 0, 0, 0);
        }
        const int o = nt * 16 + n16;
        const float bo = bias[o];
#pragma unroll
        for (int r = 0; r < 4; ++r) {
            const int m = quad * 4 + r;
            const float val = acc[r] + degf[m] * bo;
            if (OUT_BF16)
                outb[(size_t)(vbase + m) * D + o] = f32_to_bf16_rne(val);
            else
                outf[(size_t)(vbase + m) * D + o] = val;
        }
    }
}

extern "C" void kernel_launch(void* const* d_in, const int* in_sizes, int n_in,
                              void* d_out, int out_size, void* d_ws, size_t ws_size,
                              hipStream_t stream) {
    const float* x  = (const float*)d_in[0];
    const float* W1 = (const float*)d_in[1];
    const float* b1 = (const float*)d_in[2];
    const float* W2 = (const float*)d_in[3];
    const float* b2 = (const float*)d_in[4];
    const float* W3 = (const float*)d_in[5];
    const float* b3 = (const float*)d_in[6];
    const int*   ei = (const int*)d_in[7];      // [2, E] int32
    // d_in[8] = edge_index_inter — unused by the reference

    const int* src = ei;            // row 0
    const int* dst = ei + N_EDGES;  // row 1
    float* out = (float*)d_out;

    // workspace layout (256B-aligned slabs)
    char* ws = (char*)d_ws;
    int* counts  = (int*)ws;                      ws += 204800;               // N ints
    int* offsets = (int*)ws;                      ws += 204800;               // N+1 ints
    int* cursor  = (int*)ws;                      ws += 204800;               // N ints
    int* bsum    = (int*)ws;                      ws += 1024;
    int* bpre    = (int*)ws;                      ws += 1024;
    int* esrc    = (int*)ws;                      ws += (size_t)N_EDGES * 4;  // 3.2MB
    unsigned short* Wb = (unsigned short*)ws;     ws += 3 * 16384 * 2;        // 96KB
    unsigned short* xb = (unsigned short*)ws;     ws += (size_t)N_NODES * D * 2;
    unsigned short* h1 = (unsigned short*)ws;     ws += (size_t)N_NODES * D * 2;
    unsigned short* h2 = (unsigned short*)ws;

    // ---- CSR build (once; reused by all 3 layers) ----
    hipMemsetAsync(counts, 0, N_NODES * sizeof(int), stream);
    count_kernel<<<(N_EDGES + 255) / 256, 256, 0, stream>>>(dst, counts);
    block_sum_kernel<<<SCAN_BLOCKS, 256, 0, stream>>>(counts, bsum);
    bsum_scan_kernel<<<1, 256, 0, stream>>>(bsum, bpre, offsets);
    scatter_offsets_kernel<<<SCAN_BLOCKS, 256, 0, stream>>>(counts, bpre, offsets, cursor);
    fill_kernel<<<(N_EDGES + 255) / 256, 256, 0, stream>>>(src, dst, cursor, esrc);

    // weight fragments + x -> bf16
    wfrag_kernel<<<3 * 128, 128, 0, stream>>>(W1, W2, W3, Wb);
    cvt_bf16_kernel<<<(N_NODES * D / 4 + 255) / 256, 256, 0, stream>>>(x, xb);

    const int blocks = N_NODES / TN;   // 3125

    gnn_layer_kernel<true ><<<blocks, 256, 0, stream>>>(xb, offsets, esrc, Wb,          b1, nullptr, h1);
    gnn_layer_kernel<true ><<<blocks, 256, 0, stream>>>(h1, offsets, esrc, Wb + 16384,  b2, nullptr, h2);
    gnn_layer_kernel<false><<<blocks, 256, 0, stream>>>(h2, offsets, esrc, Wb + 32768,  b3, out, nullptr);
}

// Round 5
// 289.418 us; speedup vs baseline: 5.1314x; 1.2916x over previous
//
#include <hip/hip_runtime.h>

#define N_NODES 50000
#define N_EDGES 800000
#define D 128
#define TN 16                 // nodes per block in the fused layer kernel
#define TSTR 136              // LDS row stride in bf16 elems (272B: 16B-aligned)
#define SCAN_BLOCKS 196       // ceil(50000/256)

typedef __attribute__((ext_vector_type(8))) short bf16x8;
typedef __attribute__((ext_vector_type(4))) float f32x4;

__device__ __forceinline__ unsigned short f32_to_bf16_rne(float f) {
    unsigned u = __float_as_uint(f);
    u += 0x7fffu + ((u >> 16) & 1u);
    return (unsigned short)(u >> 16);
}

// ---------------------------------------------------------------------------
// prep: counts[dst[e]]++ (edge histogram)  AND  x fp32 -> bf16 (8 elems/thread)
// grid: 800K threads covers both jobs exactly (6.4M elems / 8 = 800K)
// ---------------------------------------------------------------------------
__global__ void prep_kernel(const int* __restrict__ dst, int* __restrict__ counts,
                            const float* __restrict__ x, unsigned short* __restrict__ xb) {
    const int t = blockIdx.x * blockDim.x + threadIdx.x;
    if (t < N_EDGES) atomicAdd(&counts[dst[t]], 1);
    {
        const float4 v0 = *(const float4*)(x + (size_t)t * 8);
        const float4 v1 = *(const float4*)(x + (size_t)t * 8 + 4);
        uint4 p;
        p.x = (unsigned)f32_to_bf16_rne(v0.x) | ((unsigned)f32_to_bf16_rne(v0.y) << 16);
        p.y = (unsigned)f32_to_bf16_rne(v0.z) | ((unsigned)f32_to_bf16_rne(v0.w) << 16);
        p.z = (unsigned)f32_to_bf16_rne(v1.x) | ((unsigned)f32_to_bf16_rne(v1.y) << 16);
        p.w = (unsigned)f32_to_bf16_rne(v1.z) | ((unsigned)f32_to_bf16_rne(v1.w) << 16);
        *(uint4*)(xb + (size_t)t * 8) = p;
    }
}

// ---------------------------------------------------------------------------
// Scan A: per-block (256-wide) sums of counts -> bsum[196]
// ---------------------------------------------------------------------------
__global__ void block_sum_kernel(const int* __restrict__ counts, int* __restrict__ bsum) {
    __shared__ int red[256];
    const int tid = threadIdx.x;
    const int i = blockIdx.x * 256 + tid;
    red[tid] = (i < N_NODES) ? counts[i] : 0;
    __syncthreads();
    for (int s = 128; s > 0; s >>= 1) {
        if (tid < s) red[tid] += red[tid + s];
        __syncthreads();
    }
    if (tid == 0) bsum[blockIdx.x] = red[0];
}

// ---------------------------------------------------------------------------
// Scan B: exclusive scan of the 196 block sums (single tiny block)
// ---------------------------------------------------------------------------
__global__ void bsum_scan_kernel(const int* __restrict__ bsum,
                                 int* __restrict__ bpre,
                                 int* __restrict__ offsets) {
    __shared__ int s[256];
    const int tid = threadIdx.x;
    const int v = (tid < SCAN_BLOCKS) ? bsum[tid] : 0;
    s[tid] = v;
    __syncthreads();
    for (int off = 1; off < 256; off <<= 1) {
        int a = (tid >= off) ? s[tid - off] : 0;
        __syncthreads();
        s[tid] += a;
        __syncthreads();
    }
    bpre[tid] = s[tid] - v;
    if (tid == 255) offsets[N_NODES] = s[255];
}

// ---------------------------------------------------------------------------
// Scan C (blocks 0..195): per-block exclusive scan + block prefix -> offsets, cursor
// wfrag (blocks 196..387): pack all 3 weights as bf16 MFMA B-fragments.
//   B[k][n] for tile nt, chunk kc at Wb[((w*8+nt)*4+kc)*512 + lane*8 + j],
//   lane = quad*16+n, k = kc*32+quad*8+j, B[k][n] = W[nt*16+n][k].
// ---------------------------------------------------------------------------
__global__ void offsets_wfrag_kernel(const int* __restrict__ counts,
                                     const int* __restrict__ bpre,
                                     int* __restrict__ offsets,
                                     int* __restrict__ cursor,
                                     const float* __restrict__ W1,
                                     const float* __restrict__ W2,
                                     const float* __restrict__ W3,
                                     unsigned short* __restrict__ Wb) {
    if (blockIdx.x < SCAN_BLOCKS) {
        __shared__ int s[256];
        const int tid = threadIdx.x;
        const int i = blockIdx.x * 256 + tid;
        const int v = (i < N_NODES) ? counts[i] : 0;
        s[tid] = v;
        __syncthreads();
        for (int off = 1; off < 256; off <<= 1) {
            int a = (tid >= off) ? s[tid - off] : 0;
            __syncthreads();
            s[tid] += a;
            __syncthreads();
        }
        const int excl = s[tid] - v + bpre[blockIdx.x];
        if (i < N_NODES) {
            offsets[i] = excl;
            cursor[i] = excl;
        }
    } else {
        const int unit = (blockIdx.x - SCAN_BLOCKS) * 2 + (threadIdx.x >> 7); // 0..383
        const int w = unit >> 7;
        const int o = unit & 127;
        const int k = threadIdx.x & 127;
        const float* W = (w == 0) ? W1 : (w == 1) ? W2 : W3;
        const unsigned short v = f32_to_bf16_rne(W[o * D + k]);
        const int nt = o >> 4, n = o & 15;
        const int kc = k >> 5, kr = k & 31, quad = kr >> 3, j = kr & 7;
        const int lane = quad * 16 + n;
        Wb[(((size_t)w * 8 + nt) * 4 + kc) * 512 + lane * 8 + j] = v;
    }
}

// ---------------------------------------------------------------------------
// CSR build step 3: bucket the source node of every edge by its dst
// ---------------------------------------------------------------------------
__global__ void fill_kernel(const int* __restrict__ src, const int* __restrict__ dst,
                            int* __restrict__ cursor, int* __restrict__ esrc) {
    int e = blockIdx.x * blockDim.x + threadIdx.x;
    if (e < N_EDGES) {
        int v = dst[e];
        int p = atomicAdd(&cursor[v], 1);
        esrc[p] = src[e];
    }
}

// ---------------------------------------------------------------------------
// Fused layer: out[v] = (sum h[src_e] - deg[v]*h[v]) @ W^T + deg[v]*b
// Phase 1 gather: per node, ONE coalesced load pulls <=64 edge indices into
//   per-lane regs; __shfl broadcasts them (no dependent index loads). 8 edges
//   per iter = 4 independent uint2 row-loads in flight per thread, 4 acc sets.
//   Edge pairing across half-waves; shfl_xor(32) combine; t -> LDS bf16.
// Phase 2: 16x128x128 GEMM via 8 v_mfma_f32_16x16x32_bf16 per wave.
// ---------------------------------------------------------------------------
template <bool OUT_BF16>
__global__ __launch_bounds__(256) void gnn_layer_kernel(
    const unsigned short* __restrict__ hb,     // [N][D] bf16
    const int* __restrict__ offsets,
    const int* __restrict__ esrc,
    const unsigned short* __restrict__ Wb,     // fragment-ordered bf16 (this layer)
    const float* __restrict__ bias,
    float* __restrict__ outf,
    unsigned short* __restrict__ outb) {

    __shared__ __align__(16) unsigned short tb[TN][TSTR];
    __shared__ float degf[TN];

    const int tid = threadIdx.x;
    const int wave = tid >> 6;
    const int lane = tid & 63;
    const int sub = lane >> 5;        // edge parity within pair
    const int q = lane & 31;          // dim group: dims 4q..4q+3
    const int vbase = blockIdx.x * TN;

    // ---- phase 1: gather ----
    for (int j = wave * 4; j < wave * 4 + 4; ++j) {
        const int v = vbase + j;
        const int beg = offsets[v];
        const int end = offsets[v + 1];
        const int deg = end - beg;

        float a0x = 0.f, a0y = 0.f, a0z = 0.f, a0w = 0.f;
        float a1x = 0.f, a1y = 0.f, a1z = 0.f, a1w = 0.f;
        float a2x = 0.f, a2y = 0.f, a2z = 0.f, a2w = 0.f;
        float a3x = 0.f, a3y = 0.f, a3z = 0.f, a3w = 0.f;

        if (deg <= 64) {
            // all edge indices for this node in one coalesced load
            int myidx = 0;
            if (lane < deg) myidx = esrc[beg + lane];

            int i = 0;
            for (; i + 8 <= deg; i += 8) {
                const int s0 = __shfl(myidx, i + sub, 64);
                const int s1 = __shfl(myidx, i + 2 + sub, 64);
                const int s2 = __shfl(myidx, i + 4 + sub, 64);
                const int s3 = __shfl(myidx, i + 6 + sub, 64);
                const uint2 r0 = *(const uint2*)(hb + (size_t)s0 * D + 4 * q);
                const uint2 r1 = *(const uint2*)(hb + (size_t)s1 * D + 4 * q);
                const uint2 r2 = *(const uint2*)(hb + (size_t)s2 * D + 4 * q);
                const uint2 r3 = *(const uint2*)(hb + (size_t)s3 * D + 4 * q);
                a0x += __uint_as_float(r0.x << 16); a0y += __uint_as_float(r0.x & 0xffff0000u);
                a0z += __uint_as_float(r0.y << 16); a0w += __uint_as_float(r0.y & 0xffff0000u);
                a1x += __uint_as_float(r1.x << 16); a1y += __uint_as_float(r1.x & 0xffff0000u);
                a1z += __uint_as_float(r1.y << 16); a1w += __uint_as_float(r1.y & 0xffff0000u);
                a2x += __uint_as_float(r2.x << 16); a2y += __uint_as_float(r2.x & 0xffff0000u);
                a2z += __uint_as_float(r2.y << 16); a2w += __uint_as_float(r2.y & 0xffff0000u);
                a3x += __uint_as_float(r3.x << 16); a3y += __uint_as_float(r3.x & 0xffff0000u);
                a3z += __uint_as_float(r3.y << 16); a3w += __uint_as_float(r3.y & 0xffff0000u);
            }
            for (; i + 2 <= deg; i += 2) {
                const int s0 = __shfl(myidx, i + sub, 64);
                const uint2 r0 = *(const uint2*)(hb + (size_t)s0 * D + 4 * q);
                a0x += __uint_as_float(r0.x << 16); a0y += __uint_as_float(r0.x & 0xffff0000u);
                a0z += __uint_as_float(r0.y << 16); a0w += __uint_as_float(r0.y & 0xffff0000u);
            }
            if (i < deg) {                       // wave-uniform condition
                const int s0 = __shfl(myidx, i, 64);
                if (sub == 0) {
                    const uint2 r0 = *(const uint2*)(hb + (size_t)s0 * D + 4 * q);
                    a0x += __uint_as_float(r0.x << 16); a0y += __uint_as_float(r0.x & 0xffff0000u);
                    a0z += __uint_as_float(r0.y << 16); a0w += __uint_as_float(r0.y & 0xffff0000u);
                }
            }
        } else {
            // rare high-degree fallback (dependent index loads)
            for (int e = beg; e < end; e += 2) {
                const int e0 = e + sub;
                if (e0 < end) {
                    const uint2 r0 = *(const uint2*)(hb + (size_t)esrc[e0] * D + 4 * q);
                    a0x += __uint_as_float(r0.x << 16); a0y += __uint_as_float(r0.x & 0xffff0000u);
                    a0z += __uint_as_float(r0.y << 16); a0w += __uint_as_float(r0.y & 0xffff0000u);
                }
            }
        }

        float ax = (a0x + a1x) + (a2x + a3x);
        float ay = (a0y + a1y) + (a2y + a3y);
        float az = (a0z + a1z) + (a2z + a3z);
        float aw = (a0w + a1w) + (a2w + a3w);

        ax += __shfl_xor(ax, 32, 64);
        ay += __shfl_xor(ay, 32, 64);
        az += __shfl_xor(az, 32, 64);
        aw += __shfl_xor(aw, 32, 64);

        const float dv = (float)deg;
        if (sub == 0) {
            const uint2 r = *(const uint2*)(hb + (size_t)v * D + 4 * q);
            const float tx = ax - dv * __uint_as_float(r.x << 16);
            const float ty = ay - dv * __uint_as_float(r.x & 0xffff0000u);
            const float tz = az - dv * __uint_as_float(r.y << 16);
            const float tw = aw - dv * __uint_as_float(r.y & 0xffff0000u);
            unsigned p0 = (unsigned)f32_to_bf16_rne(tx) | ((unsigned)f32_to_bf16_rne(ty) << 16);
            unsigned p1 = (unsigned)f32_to_bf16_rne(tz) | ((unsigned)f32_to_bf16_rne(tw) << 16);
            *(uint2*)&tb[j][4 * q] = make_uint2(p0, p1);
        }
        if (lane == 0) degf[j] = dv;
    }
    __syncthreads();

    // ---- phase 2: MFMA GEMM  out[16][128] = t[16][128] @ Wt[128][128] ----
    const int n16 = lane & 15;
    const int quad = lane >> 4;

    bf16x8 afrag[4];
#pragma unroll
    for (int kc = 0; kc < 4; ++kc)
        afrag[kc] = *(const bf16x8*)&tb[n16][kc * 32 + quad * 8];

#pragma unroll
    for (int i = 0; i < 2; ++i) {
        const int nt = wave * 2 + i;
        f32x4 acc = {0.f, 0.f, 0.f, 0.f};
#pragma unroll
        for (int kc = 0; kc < 4; ++kc) {
            const bf16x8 bfrag = *(const bf16x8*)&Wb[((nt * 4 + kc) * 64 + lane) * 8];
            acc = __builtin_amdgcn_mfma_f32_16x16x32_bf16(afrag[kc], bfrag, acc, 0, 0, 0);
        }
        const int o = nt * 16 + n16;
        const float bo = bias[o];
#pragma unroll
        for (int r = 0; r < 4; ++r) {
            const int m = quad * 4 + r;
            const float val = acc[r] + degf[m] * bo;
            if (OUT_BF16)
                outb[(size_t)(vbase + m) * D + o] = f32_to_bf16_rne(val);
            else
                outf[(size_t)(vbase + m) * D + o] = val;
        }
    }
}

extern "C" void kernel_launch(void* const* d_in, const int* in_sizes, int n_in,
                              void* d_out, int out_size, void* d_ws, size_t ws_size,
                              hipStream_t stream) {
    const float* x  = (const float*)d_in[0];
    const float* W1 = (const float*)d_in[1];
    const float* b1 = (const float*)d_in[2];
    const float* W2 = (const float*)d_in[3];
    const float* b2 = (const float*)d_in[4];
    const float* W3 = (const float*)d_in[5];
    const float* b3 = (const float*)d_in[6];
    const int*   ei = (const int*)d_in[7];      // [2, E] int32
    // d_in[8] = edge_index_inter — unused by the reference

    const int* src = ei;            // row 0
    const int* dst = ei + N_EDGES;  // row 1
    float* out = (float*)d_out;

    // workspace layout (256B-aligned slabs)
    char* ws = (char*)d_ws;
    int* counts  = (int*)ws;                      ws += 204800;               // N ints
    int* offsets = (int*)ws;                      ws += 204800;               // N+1 ints
    int* cursor  = (int*)ws;                      ws += 204800;               // N ints
    int* bsum    = (int*)ws;                      ws += 1024;
    int* bpre    = (int*)ws;                      ws += 1024;
    int* esrc    = (int*)ws;                      ws += (size_t)N_EDGES * 4;  // 3.2MB
    unsigned short* Wb = (unsigned short*)ws;     ws += 3 * 16384 * 2;        // 96KB
    unsigned short* xb = (unsigned short*)ws;     ws += (size_t)N_NODES * D * 2;
    unsigned short* h1 = (unsigned short*)ws;     ws += (size_t)N_NODES * D * 2;
    unsigned short* h2 = (unsigned short*)ws;

    // ---- CSR build + cvt + weight pack ----
    hipMemsetAsync(counts, 0, N_NODES * sizeof(int), stream);
    prep_kernel<<<(N_EDGES + 255) / 256, 256, 0, stream>>>(dst, counts, x, xb);
    block_sum_kernel<<<SCAN_BLOCKS, 256, 0, stream>>>(counts, bsum);
    bsum_scan_kernel<<<1, 256, 0, stream>>>(bsum, bpre, offsets);
    offsets_wfrag_kernel<<<SCAN_BLOCKS + 192, 256, 0, stream>>>(counts, bpre, offsets, cursor,
                                                                W1, W2, W3, Wb);
    fill_kernel<<<(N_EDGES + 255) / 256, 256, 0, stream>>>(src, dst, cursor, esrc);

    const int blocks = N_NODES / TN;   // 3125

    gnn_layer_kernel<true ><<<blocks, 256, 0, stream>>>(xb, offsets, esrc, Wb,          b1, nullptr, h1);
    gnn_layer_kernel<true ><<<blocks, 256, 0, stream>>>(h1, offsets, esrc, Wb + 16384,  b2, nullptr, h2);
    gnn_layer_kernel<false><<<blocks, 256, 0, stream>>>(h2, offsets, esrc, Wb + 32768,  b3, out, nullptr);
}